// Round 14
// baseline (534.147 us; speedup 1.0000x reference)
//
#include <hip/hip_runtime.h>
#include <hip/hip_bf16.h>
#include <hip/hip_fp16.h>
#include <math.h>

#define HDIM 128
#define INVD 16
#define DIN 272           // 2*H + INV
#define NKT 9             // K steps of 32 -> 288 (pad 272->288)
#define PACKSH (NKT * 8 * 64 * 8)   // 36864 shorts = 73728 B

typedef __attribute__((ext_vector_type(4))) float f32x4;
typedef __attribute__((ext_vector_type(8))) short bf16x8;
typedef __attribute__((ext_vector_type(2))) __fp16 fp16x2;

__device__ inline short f2bf(float f) {
    union { float f; unsigned u; } v; v.f = f;
    unsigned r = v.u + 0x7FFFu + ((v.u >> 16) & 1u);   // RNE
    return (short)(r >> 16);
}

__device__ inline unsigned cvt_pk_bf16(float a, float b) {   // lo=a, hi=b, RNE
    unsigned r;
    asm("v_cvt_pk_bf16_f32 %0, %1, %2" : "=v"(r) : "v"(a), "v"(b));
    return r;
}

__device__ inline float fast_rcp(float x) {                  // v_rcp_f32, ~1ulp
    float r;
    asm("v_rcp_f32 %0, %1" : "=v"(r) : "v"(x));
    return r;
}

// ---- prep: BN-fold W1 into bf16 MFMA fragment table (GLOBAL) + bias ----
__global__ __launch_bounds__(256) void prep_kernel(
    const float* __restrict__ bn_gamma, const float* __restrict__ bn_beta,
    const float* __restrict__ bn_mean,  const float* __restrict__ bn_var,
    const float* __restrict__ W1,       const float* __restrict__ b1,
    short* __restrict__ W1pack, float* __restrict__ biasTg)
{
    __shared__ float scl[DIN];
    __shared__ float shf[DIN];
    __shared__ float bias2[2][HDIM];
    const int tid = threadIdx.x;

    for (int c = tid; c < DIN; c += 256) {
        float sc = bn_gamma[c] * rsqrtf(bn_var[c] + 1e-5f);
        scl[c] = sc;
        shf[c] = bn_beta[c] - bn_mean[c] * sc;
    }
    __syncthreads();

    for (int f = tid; f < NKT * 8 * 64; f += 256) {
        const int kk  = f >> 9;
        const int cb  = (f >> 6) & 7;
        const int ln  = f & 63;
        const int k0  = kk * 32 + (ln >> 4) * 8;
        const int col = cb * 16 + (ln & 15);
        bf16x8 bv;
        #pragma unroll
        for (int j = 0; j < 8; ++j) {
            const int k = k0 + j;
            float v = (k < DIN) ? scl[k] * W1[k * HDIM + col] : 0.f;
            bv[j] = f2bf(v);
        }
        *(bf16x8*)&W1pack[f * 8] = bv;
    }
    {
        const int col  = tid & 127;
        const int half = tid >> 7;
        float s = 0.f;
        for (int k = half * 136; k < half * 136 + 136; ++k)
            s += shf[k] * W1[k * HDIM + col];
        bias2[half][col] = s;
    }
    __syncthreads();
    if (tid < HDIM) biasTg[tid] = b1[tid] + bias2[0][tid] + bias2[1][tid];
}

// ---- main: ZERO LDS, zero barriers; W1 fragments stream from L2 ----
// Occupancy is VGPR-bound: launch_bounds(256,4) -> <=128 VGPR -> 4 waves/SIMD
// = 16 waves/CU, 2x the LDS-capped structure of R8..R13.
template<int MODE>   // 1 = pk-f16 to ws, 0 = scalar f32 to out
__global__ __launch_bounds__(256, 4) void etnn_kernel(
    const float* __restrict__ x_send,
    const float* __restrict__ x_rec,
    const int*   __restrict__ index,     // [2][E] int32
    const float* __restrict__ edge_attr, // [E][16]
    const float* __restrict__ W2,
    const float* __restrict__ b2,
    const short* __restrict__ W1pack,    // [9][8][64][8] bf16, BN-folded
    const float* __restrict__ biasTg,    // [128]
    float* __restrict__ out,             // [N][H] (MODE 0)
    __half* __restrict__ ws,             // [N][H] f16 accumulator (MODE 1)
    int E, int nIter)
{
    const int tid = threadIdx.x;
    const int l  = tid & 63;
    const int lr = l & 15;     // edge slot within 16
    const int lg = l >> 4;     // k-group / row-group

    float biasv[8], w2v[8];
    #pragma unroll
    for (int cb = 0; cb < 8; ++cb) {
        biasv[cb] = biasTg[cb * 16 + lr];
        w2v[cb]   = W2[cb * 16 + lr];
    }
    const float b2v = b2[0];
    const bool evn = !(lr & 1);

    const int gw = blockIdx.x * 4 + (tid >> 6);
    const int NW = gridDim.x * 4;

    for (int it = gw; it < nIter; it += NW) {
        const int e0 = it * 16;
        const int pos = e0 + lr;
        const int pc  = (pos < E) ? pos : E - 1;
        const int is = index[pc];
        const int ir = index[E + pc];

        // -------- gather: 18 independent f32x4 loads --------
        const f32x4* ps = (const f32x4*)(x_send + (size_t)is * HDIM);
        const f32x4* pr = (const f32x4*)(x_rec  + (size_t)ir * HDIM);
        f32x4 Ls[8], Lr[8], La[2];
        #pragma unroll
        for (int kk = 0; kk < 4; ++kk) {
            Ls[kk * 2]     = ps[kk * 8 + lg * 2];
            Ls[kk * 2 + 1] = ps[kk * 8 + lg * 2 + 1];
            Lr[kk * 2]     = pr[kk * 8 + lg * 2];
            Lr[kk * 2 + 1] = pr[kk * 8 + lg * 2 + 1];
        }
        if (lg < 2) {
            const f32x4* pa = (const f32x4*)(edge_attr + (size_t)pc * INVD + lg * 8);
            La[0] = pa[0]; La[1] = pa[1];
        } else {
            La[0] = (f32x4){0.f, 0.f, 0.f, 0.f};
            La[1] = (f32x4){0.f, 0.f, 0.f, 0.f};
        }

        // -------- MFMA: 9 k-steps x 8 col-blocks (B from L2) --------
        f32x4 acc[8];
        #pragma unroll
        for (int cb = 0; cb < 8; ++cb) acc[cb] = (f32x4){0.f, 0.f, 0.f, 0.f};

        #pragma unroll
        for (int kk = 0; kk < NKT; ++kk) {
            f32x4 lo = (kk < 4) ? Ls[kk * 2]     : (kk < 8) ? Lr[(kk - 4) * 2]     : La[0];
            f32x4 hi = (kk < 4) ? Ls[kk * 2 + 1] : (kk < 8) ? Lr[(kk - 4) * 2 + 1] : La[1];
            union { bf16x8 v; unsigned u[4]; } a;
            a.u[0] = cvt_pk_bf16(lo[0], lo[1]);
            a.u[1] = cvt_pk_bf16(lo[2], lo[3]);
            a.u[2] = cvt_pk_bf16(hi[0], hi[1]);
            a.u[3] = cvt_pk_bf16(hi[2], hi[3]);
            #pragma unroll
            for (int cb = 0; cb < 8; ++cb) {
                bf16x8 b = *(const bf16x8*)&W1pack[((kk * 8 + cb) * 64 + l) * 8];
                acc[cb] = __builtin_amdgcn_mfma_f32_16x16x32_bf16(a.v, b, acc[cb], 0, 0, 0);
            }
        }

        // -------- SiLU + gate dot (16-lane reduce) --------
        float p[4] = {0.f, 0.f, 0.f, 0.f};
        #pragma unroll
        for (int cb = 0; cb < 8; ++cb) {
            #pragma unroll
            for (int q = 0; q < 4; ++q) {
                float z = acc[cb][q] + biasv[cb];
                float m = z * fast_rcp(1.f + __expf(-z));   // SiLU
                acc[cb][q] = m;
                p[q] += m * w2v[cb];
            }
        }
        #pragma unroll
        for (int q = 0; q < 4; ++q) {
            p[q] += __shfl_xor(p[q], 1, 64);
            p[q] += __shfl_xor(p[q], 2, 64);
            p[q] += __shfl_xor(p[q], 4, 64);
            p[q] += __shfl_xor(p[q], 8, 64);
        }

        // -------- gated scatter --------
        #pragma unroll
        for (int q = 0; q < 4; ++q) {
            const int row = lg * 4 + q;
            if (e0 + row < E) {
                const int irq = __shfl(ir, row, 64);
                const float g = fast_rcp(1.f + __expf(-(p[q] + b2v)));
                if constexpr (MODE == 1) {
                    float m[8];
                    #pragma unroll
                    for (int cb = 0; cb < 8; ++cb) m[cb] = acc[cb][q] * g;
                    #pragma unroll
                    for (int c = 0; c < 4; ++c) {
                        float x0 = __shfl_xor(m[2 * c],     1, 64);
                        float x1 = __shfl_xor(m[2 * c + 1], 1, 64);
                        float va = evn ? m[2 * c] : x1;
                        float vb = evn ? x0       : m[2 * c + 1];
                        union { fp16x2 h; unsigned u; } pk;
                        pk.h = __builtin_amdgcn_cvt_pkrtz(va, vb);
                        const int col0 = evn ? (32 * c + lr) : (32 * c + 15 + lr);
                        unsigned long long a =
                            (unsigned long long)(ws + (size_t)irq * HDIM + col0);
                        asm volatile("global_atomic_pk_add_f16 %0, %1, off"
                                     :: "v"(a), "v"(pk.u) : "memory");
                    }
                } else {
                    float* orow = out + (size_t)irq * HDIM + lr;
                    #pragma unroll
                    for (int cb = 0; cb < 8; ++cb)
                        atomicAdd(orow + cb * 16, acc[cb][q] * g);
                }
            }
        }
    }
}

__global__ __launch_bounds__(256) void cvt_kernel(const __half* __restrict__ ws,
                                                  float* __restrict__ out, int n) {
    int i = (blockIdx.x * 256 + threadIdx.x) * 4;
    if (i < n) {
        const __half2* p = (const __half2*)(ws + i);
        float2 a = __half22float2(p[0]);
        float2 b = __half22float2(p[1]);
        f32x4 v = {a.x, a.y, b.x, b.y};
        *(f32x4*)(out + i) = v;
    }
}

extern "C" void kernel_launch(void* const* d_in, const int* in_sizes, int n_in,
                              void* d_out, int out_size, void* d_ws, size_t ws_size,
                              hipStream_t stream) {
    const float* x_send    = (const float*)d_in[0];
    const float* x_rec     = (const float*)d_in[1];
    const int*   index     = (const int*)d_in[2];
    const float* edge_attr = (const float*)d_in[3];
    const float* bn_gamma  = (const float*)d_in[4];
    const float* bn_beta   = (const float*)d_in[5];
    const float* bn_mean   = (const float*)d_in[6];
    const float* bn_var    = (const float*)d_in[7];
    const float* W1        = (const float*)d_in[8];
    const float* b1        = (const float*)d_in[9];
    const float* W2        = (const float*)d_in[10];
    const float* b2        = (const float*)d_in[11];
    float* out = (float*)d_out;

    const int E = in_sizes[3] / INVD;
    const int N = in_sizes[0] / HDIM;
    const int nIter = (E + 15) / 16;
    const int grid = 2048;

    const size_t accBytes  = (size_t)N * HDIM * sizeof(__half);
    const size_t accAl     = (accBytes + 255) & ~(size_t)255;
    const size_t packBytes = (size_t)PACKSH * sizeof(short) + HDIM * sizeof(float);

    if (ws_size >= accAl + packBytes) {
        __half* ws   = (__half*)d_ws;
        short* pack  = (short*)((char*)d_ws + accAl);
        float* biasg = (float*)(pack + PACKSH);
        hipMemsetAsync(ws, 0, accBytes, stream);
        prep_kernel<<<1, 256, 0, stream>>>(bn_gamma, bn_beta, bn_mean, bn_var,
                                           W1, b1, pack, biasg);
        etnn_kernel<1><<<grid, 256, 0, stream>>>(x_send, x_rec, index, edge_attr,
                                                 W2, b2, pack, biasg,
                                                 out, ws, E, nIter);
        const int n = N * HDIM;
        cvt_kernel<<<(n / 4 + 255) / 256, 256, 0, stream>>>(ws, out, n);
    } else {
        // fallback: pack at ws start, scalar f32 atomics to out
        short* pack  = (short*)d_ws;
        float* biasg = (float*)(pack + PACKSH);
        hipMemsetAsync(d_out, 0, (size_t)out_size * sizeof(float), stream);
        prep_kernel<<<1, 256, 0, stream>>>(bn_gamma, bn_beta, bn_mean, bn_var,
                                           W1, b1, pack, biasg);
        etnn_kernel<0><<<grid, 256, 0, stream>>>(x_send, x_rec, index, edge_attr,
                                                 W2, b2, pack, biasg,
                                                 out, nullptr, E, nIter);
    }
}

// Round 15
// 483.528 us; speedup vs baseline: 1.1047x; 1.1047x over previous
//
#include <hip/hip_runtime.h>
#include <hip/hip_bf16.h>
#include <hip/hip_fp16.h>
#include <math.h>

#define HDIM 128
#define INVD 16
#define DIN 272           // 2*H + INV
#define NKT 9             // K steps of 32 -> 288 (pad 272->288)
#define PACKSH (NKT * 8 * 64 * 8)   // 36864 shorts = 73728 B

typedef __attribute__((ext_vector_type(4))) float f32x4;
typedef __attribute__((ext_vector_type(8))) short bf16x8;
typedef __attribute__((ext_vector_type(2))) __fp16 fp16x2;

__device__ inline short f2bf(float f) {
    union { float f; unsigned u; } v; v.f = f;
    unsigned r = v.u + 0x7FFFu + ((v.u >> 16) & 1u);   // RNE
    return (short)(r >> 16);
}

__device__ inline unsigned cvt_pk_bf16(float a, float b) {   // lo=a, hi=b, RNE
    unsigned r;
    asm("v_cvt_pk_bf16_f32 %0, %1, %2" : "=v"(r) : "v"(a), "v"(b));
    return r;
}

__device__ inline float fast_rcp(float x) {                  // v_rcp_f32, ~1ulp
    float r;
    asm("v_rcp_f32 %0, %1" : "=v"(r) : "v"(x));
    return r;
}

// ---- prep: BN-fold W1 into bf16 MFMA fragment table (GLOBAL) + bias ----
__global__ __launch_bounds__(256) void prep_kernel(
    const float* __restrict__ bn_gamma, const float* __restrict__ bn_beta,
    const float* __restrict__ bn_mean,  const float* __restrict__ bn_var,
    const float* __restrict__ W1,       const float* __restrict__ b1,
    short* __restrict__ W1pack, float* __restrict__ biasTg)
{
    __shared__ float scl[DIN];
    __shared__ float shf[DIN];
    __shared__ float bias2[2][HDIM];
    const int tid = threadIdx.x;

    for (int c = tid; c < DIN; c += 256) {
        float sc = bn_gamma[c] * rsqrtf(bn_var[c] + 1e-5f);
        scl[c] = sc;
        shf[c] = bn_beta[c] - bn_mean[c] * sc;
    }
    __syncthreads();

    for (int f = tid; f < NKT * 8 * 64; f += 256) {
        const int kk  = f >> 9;
        const int cb  = (f >> 6) & 7;
        const int ln  = f & 63;
        const int k0  = kk * 32 + (ln >> 4) * 8;
        const int col = cb * 16 + (ln & 15);
        bf16x8 bv;
        #pragma unroll
        for (int j = 0; j < 8; ++j) {
            const int k = k0 + j;
            float v = (k < DIN) ? scl[k] * W1[k * HDIM + col] : 0.f;
            bv[j] = f2bf(v);
        }
        *(bf16x8*)&W1pack[f * 8] = bv;
    }
    {
        const int col  = tid & 127;
        const int half = tid >> 7;
        float s = 0.f;
        for (int k = half * 136; k < half * 136 + 136; ++k)
            s += shf[k] * W1[k * HDIM + col];
        bias2[half][col] = s;
    }
    __syncthreads();
    if (tid < HDIM) biasTg[tid] = b1[tid] + bias2[0][tid] + bias2[1][tid];
}

// ---- main: ZERO LDS, zero barriers; W1 fragments stream from L2 ----
// launch_bounds(256,3): 3 blocks/CU -> 12 waves/CU (3/SIMD); per-wave reg
// budget ~170 so the ~124-arch-VGPR + 32-AGPR body compiles spill-free
// (R12/R14's (x,4) forced a 64/64 split -> spill; R13's LDS capped 8 waves/CU).
template<int MODE>   // 1 = pk-f16 to ws, 0 = scalar f32 to out
__global__ __launch_bounds__(256, 3) void etnn_kernel(
    const float* __restrict__ x_send,
    const float* __restrict__ x_rec,
    const int*   __restrict__ index,     // [2][E] int32
    const float* __restrict__ edge_attr, // [E][16]
    const float* __restrict__ W2,
    const float* __restrict__ b2,
    const short* __restrict__ W1pack,    // [9][8][64][8] bf16, BN-folded
    const float* __restrict__ biasTg,    // [128]
    float* __restrict__ out,             // [N][H] (MODE 0)
    __half* __restrict__ ws,             // [N][H] f16 accumulator (MODE 1)
    int E, int nIter)
{
    const int tid = threadIdx.x;
    const int l  = tid & 63;
    const int lr = l & 15;     // edge slot within 16
    const int lg = l >> 4;     // k-group / row-group

    float biasv[8], w2v[8];
    #pragma unroll
    for (int cb = 0; cb < 8; ++cb) {
        biasv[cb] = biasTg[cb * 16 + lr];
        w2v[cb]   = W2[cb * 16 + lr];
    }
    const float b2v = b2[0];
    const bool evn = !(lr & 1);

    const int gw = blockIdx.x * 4 + (tid >> 6);
    const int NW = gridDim.x * 4;

    for (int it = gw; it < nIter; it += NW) {
        const int e0 = it * 16;
        const int pos = e0 + lr;
        const int pc  = (pos < E) ? pos : E - 1;
        const int is = index[pc];
        const int ir = index[E + pc];

        // -------- gather: 18 independent f32x4 loads --------
        const f32x4* ps = (const f32x4*)(x_send + (size_t)is * HDIM);
        const f32x4* pr = (const f32x4*)(x_rec  + (size_t)ir * HDIM);
        f32x4 Ls[8], Lr[8], La[2];
        #pragma unroll
        for (int kk = 0; kk < 4; ++kk) {
            Ls[kk * 2]     = ps[kk * 8 + lg * 2];
            Ls[kk * 2 + 1] = ps[kk * 8 + lg * 2 + 1];
            Lr[kk * 2]     = pr[kk * 8 + lg * 2];
            Lr[kk * 2 + 1] = pr[kk * 8 + lg * 2 + 1];
        }
        if (lg < 2) {
            const f32x4* pa = (const f32x4*)(edge_attr + (size_t)pc * INVD + lg * 8);
            La[0] = pa[0]; La[1] = pa[1];
        } else {
            La[0] = (f32x4){0.f, 0.f, 0.f, 0.f};
            La[1] = (f32x4){0.f, 0.f, 0.f, 0.f};
        }

        // -------- MFMA: 9 k-steps x 8 col-blocks (B from L2) --------
        f32x4 acc[8];
        #pragma unroll
        for (int cb = 0; cb < 8; ++cb) acc[cb] = (f32x4){0.f, 0.f, 0.f, 0.f};

        #pragma unroll
        for (int kk = 0; kk < NKT; ++kk) {
            f32x4 lo = (kk < 4) ? Ls[kk * 2]     : (kk < 8) ? Lr[(kk - 4) * 2]     : La[0];
            f32x4 hi = (kk < 4) ? Ls[kk * 2 + 1] : (kk < 8) ? Lr[(kk - 4) * 2 + 1] : La[1];
            union { bf16x8 v; unsigned u[4]; } a;
            a.u[0] = cvt_pk_bf16(lo[0], lo[1]);
            a.u[1] = cvt_pk_bf16(lo[2], lo[3]);
            a.u[2] = cvt_pk_bf16(hi[0], hi[1]);
            a.u[3] = cvt_pk_bf16(hi[2], hi[3]);
            #pragma unroll
            for (int cb = 0; cb < 8; ++cb) {
                bf16x8 b = *(const bf16x8*)&W1pack[((kk * 8 + cb) * 64 + l) * 8];
                acc[cb] = __builtin_amdgcn_mfma_f32_16x16x32_bf16(a.v, b, acc[cb], 0, 0, 0);
            }
        }

        // -------- SiLU + gate dot (16-lane reduce) --------
        float p[4] = {0.f, 0.f, 0.f, 0.f};
        #pragma unroll
        for (int cb = 0; cb < 8; ++cb) {
            #pragma unroll
            for (int q = 0; q < 4; ++q) {
                float z = acc[cb][q] + biasv[cb];
                float m = z * fast_rcp(1.f + __expf(-z));   // SiLU
                acc[cb][q] = m;
                p[q] += m * w2v[cb];
            }
        }
        #pragma unroll
        for (int q = 0; q < 4; ++q) {
            p[q] += __shfl_xor(p[q], 1, 64);
            p[q] += __shfl_xor(p[q], 2, 64);
            p[q] += __shfl_xor(p[q], 4, 64);
            p[q] += __shfl_xor(p[q], 8, 64);
        }

        // -------- gated scatter --------
        #pragma unroll
        for (int q = 0; q < 4; ++q) {
            const int row = lg * 4 + q;
            if (e0 + row < E) {
                const int irq = __shfl(ir, row, 64);
                const float g = fast_rcp(1.f + __expf(-(p[q] + b2v)));
                if constexpr (MODE == 1) {
                    float m[8];
                    #pragma unroll
                    for (int cb = 0; cb < 8; ++cb) m[cb] = acc[cb][q] * g;
                    #pragma unroll
                    for (int c = 0; c < 4; ++c) {
                        float x0 = __shfl_xor(m[2 * c],     1, 64);
                        float x1 = __shfl_xor(m[2 * c + 1], 1, 64);
                        float va = evn ? m[2 * c] : x1;
                        float vb = evn ? x0       : m[2 * c + 1];
                        union { fp16x2 h; unsigned u; } pk;
                        pk.h = __builtin_amdgcn_cvt_pkrtz(va, vb);
                        const int col0 = evn ? (32 * c + lr) : (32 * c + 15 + lr);
                        unsigned long long a =
                            (unsigned long long)(ws + (size_t)irq * HDIM + col0);
                        asm volatile("global_atomic_pk_add_f16 %0, %1, off"
                                     :: "v"(a), "v"(pk.u) : "memory");
                    }
                } else {
                    float* orow = out + (size_t)irq * HDIM + lr;
                    #pragma unroll
                    for (int cb = 0; cb < 8; ++cb)
                        atomicAdd(orow + cb * 16, acc[cb][q] * g);
                }
            }
        }
    }
}

__global__ __launch_bounds__(256) void cvt_kernel(const __half* __restrict__ ws,
                                                  float* __restrict__ out, int n) {
    int i = (blockIdx.x * 256 + threadIdx.x) * 4;
    if (i < n) {
        const __half2* p = (const __half2*)(ws + i);
        float2 a = __half22float2(p[0]);
        float2 b = __half22float2(p[1]);
        f32x4 v = {a.x, a.y, b.x, b.y};
        *(f32x4*)(out + i) = v;
    }
}

extern "C" void kernel_launch(void* const* d_in, const int* in_sizes, int n_in,
                              void* d_out, int out_size, void* d_ws, size_t ws_size,
                              hipStream_t stream) {
    const float* x_send    = (const float*)d_in[0];
    const float* x_rec     = (const float*)d_in[1];
    const int*   index     = (const int*)d_in[2];
    const float* edge_attr = (const float*)d_in[3];
    const float* bn_gamma  = (const float*)d_in[4];
    const float* bn_beta   = (const float*)d_in[5];
    const float* bn_mean   = (const float*)d_in[6];
    const float* bn_var    = (const float*)d_in[7];
    const float* W1        = (const float*)d_in[8];
    const float* b1        = (const float*)d_in[9];
    const float* W2        = (const float*)d_in[10];
    const float* b2        = (const float*)d_in[11];
    float* out = (float*)d_out;

    const int E = in_sizes[3] / INVD;
    const int N = in_sizes[0] / HDIM;
    const int nIter = (E + 15) / 16;
    const int grid = 2048;

    const size_t accBytes  = (size_t)N * HDIM * sizeof(__half);
    const size_t accAl     = (accBytes + 255) & ~(size_t)255;
    const size_t packBytes = (size_t)PACKSH * sizeof(short) + HDIM * sizeof(float);

    if (ws_size >= accAl + packBytes) {
        __half* ws   = (__half*)d_ws;
        short* pack  = (short*)((char*)d_ws + accAl);
        float* biasg = (float*)(pack + PACKSH);
        hipMemsetAsync(ws, 0, accBytes, stream);
        prep_kernel<<<1, 256, 0, stream>>>(bn_gamma, bn_beta, bn_mean, bn_var,
                                           W1, b1, pack, biasg);
        etnn_kernel<1><<<grid, 256, 0, stream>>>(x_send, x_rec, index, edge_attr,
                                                 W2, b2, pack, biasg,
                                                 out, ws, E, nIter);
        const int n = N * HDIM;
        cvt_kernel<<<(n / 4 + 255) / 256, 256, 0, stream>>>(ws, out, n);
    } else {
        // fallback: pack at ws start, scalar f32 atomics to out
        short* pack  = (short*)d_ws;
        float* biasg = (float*)(pack + PACKSH);
        hipMemsetAsync(d_out, 0, (size_t)out_size * sizeof(float), stream);
        prep_kernel<<<1, 256, 0, stream>>>(bn_gamma, bn_beta, bn_mean, bn_var,
                                           W1, b1, pack, biasg);
        etnn_kernel<0><<<grid, 256, 0, stream>>>(x_send, x_rec, index, edge_attr,
                                                 W2, b2, pack, biasg,
                                                 out, nullptr, E, nIter);
    }
}

// Round 16
// 193.081 us; speedup vs baseline: 2.7664x; 2.5043x over previous
//
#include <hip/hip_runtime.h>
#include <hip/hip_bf16.h>
#include <hip/hip_fp16.h>
#include <math.h>

#define HDIM 128
#define INVD 16
#define DIN 272           // 2*H + INV
#define NKT 9             // K steps of 32 -> 288 (pad 272->288)

typedef __attribute__((ext_vector_type(4))) float f32x4;
typedef __attribute__((ext_vector_type(8))) short bf16x8;
typedef __attribute__((ext_vector_type(2))) __fp16 fp16x2;

__device__ inline short f2bf(float f) {
    union { float f; unsigned u; } v; v.f = f;
    unsigned r = v.u + 0x7FFFu + ((v.u >> 16) & 1u);   // RNE
    return (short)(r >> 16);
}

__device__ inline unsigned cvt_pk_bf16(float a, float b) {   // lo=a, hi=b, RNE
    unsigned r;
    asm("v_cvt_pk_bf16_f32 %0, %1, %2" : "=v"(r) : "v"(a), "v"(b));
    return r;
}

__device__ inline float fast_rcp(float x) {                  // v_rcp_f32, ~1ulp
    float r;
    asm("v_rcp_f32 %0, %1" : "=v"(r) : "v"(x));
    return r;
}

// Barrier-free main loop: each wave owns 16 edges x 128 cols.
// W1 (BN-folded bf16) fragment table in LDS, read-only after init.
// KEY CHANGE vs R8/R13: a register-liveness asm fence forces ALL 18 gather
// loads to be issued before any use -> 1 vmcnt wait per tile instead of ~9
// (compiler's reg-pressure heuristic otherwise batches loads serially).
template<int MODE>   // 1 = pk-f16 to ws, 0 = scalar f32 to out (fallback)
__global__ __launch_bounds__(256, 2) void etnn_kernel(
    const float* __restrict__ x_send,
    const float* __restrict__ x_rec,
    const int*   __restrict__ index,     // [2][E] int32
    const float* __restrict__ edge_attr, // [E][16]
    const float* __restrict__ bn_gamma,
    const float* __restrict__ bn_beta,
    const float* __restrict__ bn_mean,
    const float* __restrict__ bn_var,
    const float* __restrict__ W1,        // [DIN][H]
    const float* __restrict__ b1,
    const float* __restrict__ W2,
    const float* __restrict__ b2,
    float* __restrict__ out,             // [N][H] (MODE 0)
    __half* __restrict__ ws,             // [N][H] f16 accumulator (MODE 1)
    int E, int nIter)
{
    __shared__ short btab[NKT * 8 * 64 * 8];   // 73728 B
    __shared__ float scl[DIN];
    __shared__ float shf[DIN];
    __shared__ float bias2[2][HDIM];
    __shared__ float biasT[HDIM];

    const int tid = threadIdx.x;
    const int l  = tid & 63;
    const int lr = l & 15;     // edge slot within 16
    const int lg = l >> 4;     // k-group / row-group

    for (int c = tid; c < DIN; c += 256) {
        float sc = bn_gamma[c] * rsqrtf(bn_var[c] + 1e-5f);
        scl[c] = sc;
        shf[c] = bn_beta[c] - bn_mean[c] * sc;
    }
    __syncthreads();

    for (int f = tid; f < NKT * 8 * 64; f += 256) {
        const int kk  = f >> 9;
        const int cb  = (f >> 6) & 7;
        const int ln  = f & 63;
        const int k0  = kk * 32 + (ln >> 4) * 8;
        const int col = cb * 16 + (ln & 15);
        bf16x8 bv;
        #pragma unroll
        for (int j = 0; j < 8; ++j) {
            const int k = k0 + j;
            float v = (k < DIN) ? scl[k] * W1[k * HDIM + col] : 0.f;
            bv[j] = f2bf(v);
        }
        *(bf16x8*)&btab[f * 8] = bv;
    }
    {
        const int col  = tid & 127;
        const int half = tid >> 7;
        float s = 0.f;
        for (int k = half * 136; k < half * 136 + 136; ++k)
            s += shf[k] * W1[k * HDIM + col];
        bias2[half][col] = s;
    }
    __syncthreads();
    if (tid < HDIM) biasT[tid] = b1[tid] + bias2[0][tid] + bias2[1][tid];
    __syncthreads();
    // ---- NO barriers below; btab/biasT read-only ----

    float biasv[8], w2v[8];
    #pragma unroll
    for (int cb = 0; cb < 8; ++cb) {
        biasv[cb] = biasT[cb * 16 + lr];
        w2v[cb]   = W2[cb * 16 + lr];
    }
    const float b2v = b2[0];
    const bool evn = !(lr & 1);

    const int gw = blockIdx.x * 4 + (tid >> 6);
    const int NW = gridDim.x * 4;

    if (gw >= nIter) return;

    // preload indices for first tile
    int pc, is, ir;
    {
        int pos = gw * 16 + lr;
        pc = (pos < E) ? pos : E - 1;
        is = index[pc];
        ir = index[E + pc];
    }

    for (int it = gw; it < nIter; it += NW) {
        const int e0 = it * 16;

        // -------- issue ALL 18 gather loads --------
        const f32x4* ps = (const f32x4*)(x_send + (size_t)is * HDIM);
        const f32x4* pr = (const f32x4*)(x_rec  + (size_t)ir * HDIM);
        f32x4 Ls[8], Lr[8], La[2];
        #pragma unroll
        for (int kk = 0; kk < 4; ++kk) {
            Ls[kk * 2]     = ps[kk * 8 + lg * 2];
            Ls[kk * 2 + 1] = ps[kk * 8 + lg * 2 + 1];
            Lr[kk * 2]     = pr[kk * 8 + lg * 2];
            Lr[kk * 2 + 1] = pr[kk * 8 + lg * 2 + 1];
        }
        if (lg < 2) {
            const f32x4* pa = (const f32x4*)(edge_attr + (size_t)pc * INVD + lg * 8);
            La[0] = pa[0]; La[1] = pa[1];
        } else {
            La[0] = (f32x4){0.f, 0.f, 0.f, 0.f};
            La[1] = (f32x4){0.f, 0.f, 0.f, 0.f};
        }

        // prefetch next tile's indices while gathers are in flight
        const int irc = ir;          // current receiver (for scatter)
        {
            int itn = it + NW;
            int pos = (itn < nIter) ? itn * 16 + lr : pc;
            int pcn = (pos < E) ? pos : E - 1;
            pc = pcn;
            is = index[pcn];
            ir = index[E + pcn];
        }

        // ---- liveness fence: all 18 gather values must be materialized ----
        asm volatile("" :
            "+v"(Ls[0]), "+v"(Ls[1]), "+v"(Ls[2]), "+v"(Ls[3]),
            "+v"(Ls[4]), "+v"(Ls[5]), "+v"(Ls[6]), "+v"(Ls[7]),
            "+v"(Lr[0]), "+v"(Lr[1]), "+v"(Lr[2]), "+v"(Lr[3]),
            "+v"(Lr[4]), "+v"(Lr[5]), "+v"(Lr[6]), "+v"(Lr[7]),
            "+v"(La[0]), "+v"(La[1]));

        // -------- MFMA: 9 k-steps x 8 col-blocks --------
        f32x4 acc[8];
        #pragma unroll
        for (int cb = 0; cb < 8; ++cb) acc[cb] = (f32x4){0.f, 0.f, 0.f, 0.f};

        #pragma unroll
        for (int kk = 0; kk < NKT; ++kk) {
            f32x4 lo = (kk < 4) ? Ls[kk * 2]     : (kk < 8) ? Lr[(kk - 4) * 2]     : La[0];
            f32x4 hi = (kk < 4) ? Ls[kk * 2 + 1] : (kk < 8) ? Lr[(kk - 4) * 2 + 1] : La[1];
            union { bf16x8 v; unsigned u[4]; } a;
            a.u[0] = cvt_pk_bf16(lo[0], lo[1]);
            a.u[1] = cvt_pk_bf16(lo[2], lo[3]);
            a.u[2] = cvt_pk_bf16(hi[0], hi[1]);
            a.u[3] = cvt_pk_bf16(hi[2], hi[3]);
            #pragma unroll
            for (int cb = 0; cb < 8; ++cb) {
                bf16x8 b = *(const bf16x8*)&btab[((kk * 8 + cb) * 64 + l) * 8];
                acc[cb] = __builtin_amdgcn_mfma_f32_16x16x32_bf16(a.v, b, acc[cb], 0, 0, 0);
            }
        }

        // -------- SiLU + gate dot (16-lane reduce) --------
        float p[4] = {0.f, 0.f, 0.f, 0.f};
        #pragma unroll
        for (int cb = 0; cb < 8; ++cb) {
            #pragma unroll
            for (int q = 0; q < 4; ++q) {
                float z = acc[cb][q] + biasv[cb];
                float m = z * fast_rcp(1.f + __expf(-z));   // SiLU
                acc[cb][q] = m;
                p[q] += m * w2v[cb];
            }
        }
        #pragma unroll
        for (int q = 0; q < 4; ++q) {
            p[q] += __shfl_xor(p[q], 1, 64);
            p[q] += __shfl_xor(p[q], 2, 64);
            p[q] += __shfl_xor(p[q], 4, 64);
            p[q] += __shfl_xor(p[q], 8, 64);
        }

        // -------- gated scatter --------
        #pragma unroll
        for (int q = 0; q < 4; ++q) {
            const int row = lg * 4 + q;
            if (e0 + row < E) {
                const int irq = __shfl(irc, row, 64);
                const float g = fast_rcp(1.f + __expf(-(p[q] + b2v)));
                if constexpr (MODE == 1) {
                    float m[8];
                    #pragma unroll
                    for (int cb = 0; cb < 8; ++cb) m[cb] = acc[cb][q] * g;
                    #pragma unroll
                    for (int c = 0; c < 4; ++c) {
                        float x0 = __shfl_xor(m[2 * c],     1, 64);
                        float x1 = __shfl_xor(m[2 * c + 1], 1, 64);
                        float va = evn ? m[2 * c] : x1;
                        float vb = evn ? x0       : m[2 * c + 1];
                        union { fp16x2 h; unsigned u; } pk;
                        pk.h = __builtin_amdgcn_cvt_pkrtz(va, vb);
                        const int col0 = evn ? (32 * c + lr) : (32 * c + 15 + lr);
                        unsigned long long a =
                            (unsigned long long)(ws + (size_t)irq * HDIM + col0);
                        asm volatile("global_atomic_pk_add_f16 %0, %1, off"
                                     :: "v"(a), "v"(pk.u) : "memory");
                    }
                } else {
                    float* orow = out + (size_t)irq * HDIM + lr;
                    #pragma unroll
                    for (int cb = 0; cb < 8; ++cb)
                        atomicAdd(orow + cb * 16, acc[cb][q] * g);
                }
            }
        }
    }
}

__global__ __launch_bounds__(256) void cvt_kernel(const __half* __restrict__ ws,
                                                  float* __restrict__ out, int n) {
    int i = (blockIdx.x * 256 + threadIdx.x) * 4;
    if (i < n) {
        const __half2* p = (const __half2*)(ws + i);
        float2 a = __half22float2(p[0]);
        float2 b = __half22float2(p[1]);
        f32x4 v = {a.x, a.y, b.x, b.y};
        *(f32x4*)(out + i) = v;
    }
}

extern "C" void kernel_launch(void* const* d_in, const int* in_sizes, int n_in,
                              void* d_out, int out_size, void* d_ws, size_t ws_size,
                              hipStream_t stream) {
    const float* x_send    = (const float*)d_in[0];
    const float* x_rec     = (const float*)d_in[1];
    const int*   index     = (const int*)d_in[2];
    const float* edge_attr = (const float*)d_in[3];
    const float* bn_gamma  = (const float*)d_in[4];
    const float* bn_beta   = (const float*)d_in[5];
    const float* bn_mean   = (const float*)d_in[6];
    const float* bn_var    = (const float*)d_in[7];
    const float* W1        = (const float*)d_in[8];
    const float* b1        = (const float*)d_in[9];
    const float* W2        = (const float*)d_in[10];
    const float* b2        = (const float*)d_in[11];
    float* out = (float*)d_out;

    const int E = in_sizes[3] / INVD;
    const int N = in_sizes[0] / HDIM;
    const int nIter = (E + 15) / 16;
    const int grid = 512;   // 2 blocks/CU (LDS-limited), barrier-free waves

    const size_t accBytes = (size_t)N * HDIM * sizeof(__half);
    if (ws_size >= accBytes) {
        __half* ws = (__half*)d_ws;
        hipMemsetAsync(ws, 0, accBytes, stream);
        etnn_kernel<1><<<grid, 256, 0, stream>>>(x_send, x_rec, index, edge_attr,
                                                 bn_gamma, bn_beta, bn_mean, bn_var,
                                                 W1, b1, W2, b2, out, ws, E, nIter);
        const int n = N * HDIM;
        cvt_kernel<<<(n / 4 + 255) / 256, 256, 0, stream>>>(ws, out, n);
    } else {
        hipMemsetAsync(d_out, 0, (size_t)out_size * sizeof(float), stream);
        etnn_kernel<0><<<grid, 256, 0, stream>>>(x_send, x_rec, index, edge_attr,
                                                 bn_gamma, bn_beta, bn_mean, bn_var,
                                                 W1, b1, W2, b2, out, nullptr, E, nIter);
    }
}